// Round 1
// baseline (92.737 us; speedup 1.0000x reference)
//
#include <hip/hip_runtime.h>

// out_w(x) = (1/16) * sum_{m!=m'} G_w[m,m'] * cos(eps(m,m') . x)
//   G_w = V^T D_w V  (V = batch-uniform real variational circuit incl. CNOT chains)
//   eps_u = bit_u(m)-bit_u(m') in {-1,0,1}; diagonal drops out (trace(D_w)=0, V orthogonal).
//
// Fused single-kernel version: each block recomputes the 81-slot coefficient table
// in LDS (shfl-based V simulation: 1 shfl_xor + 1-2 VALU per gate, ~600 wave-cy/block),
// then runs the per-element trig evaluation. No workspace, no inter-kernel dependency.

typedef float v2f __attribute__((ext_vector_type(2)));

__device__ __forceinline__ v2f cm2(v2f a, v2f bv, v2f br) { return a.x * bv + a.y * br; }

__global__ __launch_bounds__(256) void qfused_kernel(
    const float* __restrict__ inputs,   // (B,4)
    const float* __restrict__ params,   // (2,4) uniform
    float* __restrict__ out,            // (B,4)
    int B)
{
    __shared__ float Vs[16][17];        // Vs[col][row] = V[row][col]; +1 pad breaks stride-16 banks
    __shared__ float4 T[81];

    const int tid = threadIdx.x;
    const int b = blockIdx.x * blockDim.x + tid;

    // issue the batch load early so HBM latency hides under the prep phase
    float4 x;
    if (b < B) x = reinterpret_cast<const float4*>(inputs)[b];

    // ---- per-block prep: simulate V's 16 columns via cross-lane shuffles ----
    // thread (c = tid>>4, r = tid&15) holds amplitude V[r][c]. Masks <= 8 keep
    // shfl partners inside the same 16-lane group (same column, same wave).
    {
        const int c = tid >> 4, r = tid & 15;
        float A = (r == c) ? 1.f : 0.f;
        auto cnot = [&](int cm, int tm) {
            float P = __shfl_xor(A, tm);
            A = (r & cm) ? P : A;
        };
        auto ry = [&](int m, float cp, float sp) {
            float P = __shfl_xor(A, m);
            A = cp * A + sp * ((r & m) ? P : -P);
        };
        cnot(8, 4); cnot(4, 2); cnot(2, 1);          // feature-map CNOT chain
        #pragma unroll
        for (int l = 0; l < 2; ++l) {
            float cp[4], sp[4];
            #pragma unroll
            for (int w = 0; w < 4; ++w) __sincosf(0.5f * params[l*4 + w], &sp[w], &cp[w]);
            ry(8, cp[0], sp[0]); ry(4, cp[1], sp[1]); ry(2, cp[2], sp[2]); ry(1, cp[3], sp[3]);
            cnot(8, 4); cnot(4, 2); cnot(2, 1); cnot(1, 8);
        }
        Vs[c][r] = A;
        if (tid < 81) T[tid] = make_float4(0.f, 0.f, 0.f, 0.f);
    }
    __syncthreads();

    // ---- build G_w grouped by canonical eps class (40 active of 81 slots) ----
    for (int it = tid; it < 1024; it += 256) {
        const int w = it >> 8, m = (it >> 4) & 15, mp = it & 15;
        if (m == mp) continue;
        int t = 0; int first = 1;
        #pragma unroll
        for (int u = 0; u < 4; ++u) {
            const int d = ((m >> (3 - u)) & 1) - ((mp >> (3 - u)) & 1) + 1;
            t = t * 3 + d;
            if (first == 1 && d != 1) first = d;
        }
        if (first != 2) continue;     // canonical ordering only (each unordered pair once)
        float g = 0.f;
        #pragma unroll
        for (int k = 0; k < 16; ++k) {
            const float sgn = ((k >> (3 - w)) & 1) ? -1.f : 1.f;
            g += sgn * Vs[m][k] * Vs[mp][k];
        }
        atomicAdd(((float*)&T[t]) + w, 0.125f * g);   // 2/16 weight folded in
    }
    __syncthreads();

    // ---- per-element evaluation (identical math to previous qmain) ----
    if (b >= B) return;   // safe: all barriers above

    v2f e[4], r[4], ec[4], rc[4];
    {
        float cc, ss;
        __sincosf(x.x, &ss, &cc); e[0] = (v2f){cc, ss};
        __sincosf(x.y, &ss, &cc); e[1] = (v2f){cc, ss};
        __sincosf(x.z, &ss, &cc); e[2] = (v2f){cc, ss};
        __sincosf(x.w, &ss, &cc); e[3] = (v2f){cc, ss};
    }
    #pragma unroll
    for (int u = 0; u < 4; ++u) {
        r[u]  = (v2f){-e[u].y, e[u].x};   // for z*e:      z.x*e + z.y*r
        ec[u] = (v2f){ e[u].x, -e[u].y};  // for z*conj(e): z.x*ec + z.y*rc
        rc[u] = (v2f){ e[u].y,  e[u].x};
    }

    // canonical prefix products over wires 0..2 (digit d = eps+1, msd first)
    v2f P2[9], P3[27];
    #pragma unroll
    for (int t = 0; t < 9; ++t) {
        const int d0 = t / 3, d1 = t % 3;
        if (d0 == 0 || (d0 == 1 && d1 == 0)) continue;
        if (d0 == 1) P2[t] = (d1 == 1) ? (v2f){1.f, 0.f} : e[1];
        else         P2[t] = (d1 == 1) ? e[0]
                           : (d1 == 2) ? cm2(e[0], e[1], r[1])
                                       : cm2(e[0], ec[1], rc[1]);
    }
    #pragma unroll
    for (int t = 0; t < 27; ++t) {
        const int d0 = t / 9, d1 = (t / 3) % 3, d2 = t % 3;
        const bool ones01 = (d0 == 1 && d1 == 1);
        if (d0 == 0 || (d0 == 1 && d1 == 0) || (ones01 && d2 == 0)) continue;
        if (ones01) P3[t] = (d2 == 1) ? (v2f){1.f, 0.f} : e[2];
        else {
            const int tp = t / 3;
            P3[t] = (d2 == 1) ? P2[tp]
                  : (d2 == 2) ? cm2(P2[tp], e[2], r[2])
                              : cm2(P2[tp], ec[2], rc[2]);
        }
    }

    v2f o01 = (v2f){0.f, 0.f}, o23 = (v2f){0.f, 0.f};
    #pragma unroll
    for (int t = 0; t < 81; ++t) {
        const int d0 = t / 27, d1 = (t / 9) % 3, d2 = (t / 3) % 3, d3 = t % 3;
        const int first = (d0 != 1) ? d0 : (d1 != 1) ? d1 : (d2 != 1) ? d2 : (d3 != 1) ? d3 : 1;
        if (first != 2) continue;                      // canonical eps only (40 slots)
        const bool ones012 = (d0 == 1 && d1 == 1 && d2 == 1);
        float cv;
        if (ones012) cv = e[3].x;                      // only d3==2 reaches here
        else {
            const int tp = t / 3;
            if (d3 == 1)      cv = P3[tp].x;
            else if (d3 == 2) cv = P3[tp].x * e[3].x - P3[tp].y * e[3].y;
            else              cv = P3[tp].x * e[3].x + P3[tp].y * e[3].y;
        }
        const float4 cf = T[t];                        // uniform-address LDS broadcast
        o01 += cv * (v2f){cf.x, cf.y};
        o23 += cv * (v2f){cf.z, cf.w};
    }

    reinterpret_cast<float4*>(out)[b] = make_float4(o01.x, o01.y, o23.x, o23.y);
}

extern "C" void kernel_launch(void* const* d_in, const int* in_sizes, int n_in,
                              void* d_out, int out_size, void* d_ws, size_t ws_size,
                              hipStream_t stream) {
    const float* inputs = (const float*)d_in[0];
    const float* params = (const float*)d_in[1];
    float* out = (float*)d_out;
    const int B = in_sizes[0] / 4;

    const int threads = 256;
    const int blocks = (B + threads - 1) / threads;
    qfused_kernel<<<blocks, threads, 0, stream>>>(inputs, params, out, B);
}

// Round 2
// 74.617 us; speedup vs baseline: 1.2428x; 1.2428x over previous
//
#include <hip/hip_runtime.h>

// out_w(x) = (1/16) * sum_{m!=m'} G_w[m,m'] * cos(eps(m,m') . x)
//   G_w = V^T D_w V  (V = batch-uniform real variational circuit incl. CNOT chains)
//   eps_u = bit_u(m)-bit_u(m') in {-1,0,1}; diagonal drops out (trace(D_w)=0, V orthogonal).
// Two-kernel structure is deliberate (round-1 lesson): the 40 coefficient broadcasts
// must come from GLOBAL memory (s_load_dwordx4, scalar pipe, ~free) — fusing prep
// per-block forces them through the LDS pipe at ~12.8 us device-wide.
// qprep (1 block, ~1 us): simulate V's 16 columns, form G_w, group by canonical eps
// (first nonzero digit = +1; 40 classes) into an 81-slot x float4 table in d_ws.
// qmain: 4 sincos + canonical product tree + prefix-grouped 40-term dot.

typedef float v2f __attribute__((ext_vector_type(2)));

__global__ void qprep_kernel(const float* __restrict__ params, float* __restrict__ tab) {
    __shared__ float V[16][16];   // V[row][col]
    __shared__ float4 T[81];
    const int tid = threadIdx.x;
    if (tid < 81) T[tid] = make_float4(0.f, 0.f, 0.f, 0.f);
    if (tid < 16) {
        float col[16];
        #pragma unroll
        for (int j = 0; j < 16; ++j) col[j] = (j == tid) ? 1.f : 0.f;
        auto cnot = [&](int cm, int tm) {
            #pragma unroll
            for (int j = 0; j < 16; ++j)
                if ((j & cm) && !(j & tm)) { int k = j | tm; float t0 = col[j]; col[j] = col[k]; col[k] = t0; }
        };
        auto ry = [&](int m, float c, float s) {
            #pragma unroll
            for (int j = 0; j < 16; ++j)
                if (!(j & m)) { int k = j | m; float a0 = col[j], a1 = col[k]; col[j] = c*a0 - s*a1; col[k] = s*a0 + c*a1; }
        };
        cnot(8, 4); cnot(4, 2); cnot(2, 1);          // feature-map CNOT chain
        #pragma unroll
        for (int l = 0; l < 2; ++l) {
            float cp[4], sp[4];
            #pragma unroll
            for (int w = 0; w < 4; ++w) __sincosf(0.5f * params[l*4 + w], &sp[w], &cp[w]);
            ry(8, cp[0], sp[0]); ry(4, cp[1], sp[1]); ry(2, cp[2], sp[2]); ry(1, cp[3], sp[3]);
            cnot(8, 4); cnot(4, 2); cnot(2, 1); cnot(1, 8);
        }
        #pragma unroll
        for (int j = 0; j < 16; ++j) V[j][tid] = col[j];
    }
    __syncthreads();
    for (int it = tid; it < 1024; it += 256) {
        const int w = it >> 8, m = (it >> 4) & 15, mp = it & 15;
        if (m == mp) continue;
        int t = 0; int first = 1;
        #pragma unroll
        for (int u = 0; u < 4; ++u) {
            const int d = ((m >> (3 - u)) & 1) - ((mp >> (3 - u)) & 1) + 1;
            t = t * 3 + d;
            if (first == 1 && d != 1) first = d;
        }
        if (first != 2) continue;     // keep canonical ordering only (covers each unordered pair once)
        float g = 0.f;
        #pragma unroll
        for (int k = 0; k < 16; ++k) {
            const float sgn = ((k >> (3 - w)) & 1) ? -1.f : 1.f;
            g += sgn * V[k][m] * V[k][mp];
        }
        atomicAdd(((float*)&T[t]) + w, 0.125f * g);   // 2/16 weight folded in
    }
    __syncthreads();
    if (tid < 81) reinterpret_cast<float4*>(tab)[tid] = T[tid];
}

__device__ __forceinline__ v2f cm2(v2f a, v2f bv, v2f br) { return a.x * bv + a.y * br; }

__global__ __launch_bounds__(256) void qmain_kernel(
    const float* __restrict__ inputs,   // (B,4)
    const float4* __restrict__ tab,     // 81 x float4 coefficients (uniform)
    float* __restrict__ out,            // (B,4)
    int B)
{
    const int b = blockIdx.x * blockDim.x + threadIdx.x;
    if (b >= B) return;
    const float4 x = reinterpret_cast<const float4*>(inputs)[b];

    v2f e[4], r[4], ec[4], rc[4];
    {
        float cc, ss;
        __sincosf(x.x, &ss, &cc); e[0] = (v2f){cc, ss};
        __sincosf(x.y, &ss, &cc); e[1] = (v2f){cc, ss};
        __sincosf(x.z, &ss, &cc); e[2] = (v2f){cc, ss};
        __sincosf(x.w, &ss, &cc); e[3] = (v2f){cc, ss};
    }
    #pragma unroll
    for (int u = 0; u < 3; ++u) {
        r[u]  = (v2f){-e[u].y, e[u].x};   // for z*e:      z.x*e + z.y*r
        ec[u] = (v2f){ e[u].x, -e[u].y};  // for z*conj(e): z.x*ec + z.y*rc
        rc[u] = (v2f){ e[u].y,  e[u].x};
    }

    // canonical prefix products over wires 0..2 (digit d = eps+1, msd first)
    v2f P2[9], P3[27];
    #pragma unroll
    for (int t = 0; t < 9; ++t) {
        const int d0 = t / 3, d1 = t % 3;
        if (d0 == 0 || (d0 == 1 && d1 == 0)) continue;
        if (d0 == 1) P2[t] = (d1 == 1) ? (v2f){1.f, 0.f} : e[1];
        else         P2[t] = (d1 == 1) ? e[0]
                           : (d1 == 2) ? cm2(e[0], e[1], r[1])
                                       : cm2(e[0], ec[1], rc[1]);
    }
    #pragma unroll
    for (int t = 0; t < 27; ++t) {
        const int d0 = t / 9, d1 = (t / 3) % 3, d2 = t % 3;
        const bool ones01 = (d0 == 1 && d1 == 1);
        if (d0 == 0 || (d0 == 1 && d1 == 0) || (ones01 && d2 == 0)) continue;
        if (ones01) P3[t] = (d2 == 1) ? (v2f){1.f, 0.f} : e[2];
        else {
            const int tp = t / 3;
            P3[t] = (d2 == 1) ? P2[tp]
                  : (d2 == 2) ? cm2(P2[tp], e[2], r[2])
                              : cm2(P2[tp], ec[2], rc[2]);
        }
    }

    // final 40-term dot, grouped by P3 prefix so pc/ps are shared across d3 digits:
    //   d3==1: cv = Re(P3);  d3==2 (eps3=+1): cv = pc - ps;  d3==0 (eps3=-1): cv = pc + ps
    const float e3x = e[3].x, e3y = e[3].y;
    v2f o01 = (v2f){0.f, 0.f}, o23 = (v2f){0.f, 0.f};
    #pragma unroll
    for (int tp = 0; tp < 27; ++tp) {
        const int d0 = tp / 9, d1 = (tp / 3) % 3, d2 = tp % 3;
        const int first = (d0 != 1) ? d0 : (d1 != 1) ? d1 : (d2 != 1) ? d2 : 1;
        if (first == 0) continue;                      // non-canonical prefix
        if (first == 1) {                              // all-ones prefix: only d3==2 survives
            const float4 cf = tab[tp*3 + 2];
            o01 += e3x * (v2f){cf.x, cf.y};
            o23 += e3x * (v2f){cf.z, cf.w};
            continue;
        }
        const float pc = P3[tp].x * e3x, ps = P3[tp].y * e3y;
        const float cv1 = P3[tp].x, cv2 = pc - ps, cv0 = pc + ps;
        { const float4 cf = tab[tp*3 + 1]; o01 += cv1*(v2f){cf.x,cf.y}; o23 += cv1*(v2f){cf.z,cf.w}; }
        { const float4 cf = tab[tp*3 + 2]; o01 += cv2*(v2f){cf.x,cf.y}; o23 += cv2*(v2f){cf.z,cf.w}; }
        { const float4 cf = tab[tp*3 + 0]; o01 += cv0*(v2f){cf.x,cf.y}; o23 += cv0*(v2f){cf.z,cf.w}; }
    }

    reinterpret_cast<float4*>(out)[b] = make_float4(o01.x, o01.y, o23.x, o23.y);
}

extern "C" void kernel_launch(void* const* d_in, const int* in_sizes, int n_in,
                              void* d_out, int out_size, void* d_ws, size_t ws_size,
                              hipStream_t stream) {
    const float* inputs = (const float*)d_in[0];
    const float* params = (const float*)d_in[1];
    float* out = (float*)d_out;
    float* tab = (float*)d_ws;                 // 81*4 floats = 1296 B
    const int B = in_sizes[0] / 4;

    qprep_kernel<<<1, 256, 0, stream>>>(params, tab);
    const int threads = 256;
    const int blocks = (B + threads - 1) / threads;
    qmain_kernel<<<blocks, threads, 0, stream>>>(inputs, (const float4*)tab, out, B);
}